// Round 1
// baseline (13089.600 us; speedup 1.0000x reference)
//
#include <hip/hip_runtime.h>
#include <math.h>

#define B_ 8
#define N_ 20000
#define E_ 40000
#define H_ 128
#define L_ 4
#define A_ 4

__device__ __forceinline__ float silu_f(float x) { return x / (1.f + __expf(-x)); }

// ---------------- setup kernels ----------------

__global__ void k_zero(int* __restrict__ deg, int* __restrict__ cursor) {
    int i = blockIdx.x * 256 + threadIdx.x;
    if (i < N_) { deg[i] = 0; cursor[i] = 0; }
}

__global__ void k_deg(const int* __restrict__ bond, int* __restrict__ deg) {
    int e = blockIdx.x * 256 + threadIdx.x;
    if (e < E_) {
        atomicAdd(&deg[bond[2 * e]], 1);
        atomicAdd(&deg[bond[2 * e + 1]], 1);
    }
}

__global__ void k_scan(const int* __restrict__ deg, int* __restrict__ indptr) {
    __shared__ int sums[1024];
    const int CH = (N_ + 1023) / 1024;  // 20
    int t = threadIdx.x;
    int s0 = t * CH;
    int s1 = min(s0 + CH, N_);
    int s = 0;
    for (int i = s0; i < s1; ++i) s += deg[i];
    sums[t] = s;
    __syncthreads();
    for (int off = 1; off < 1024; off <<= 1) {
        int v = (t >= off) ? sums[t - off] : 0;
        __syncthreads();
        sums[t] += v;
        __syncthreads();
    }
    int base = (t > 0) ? sums[t - 1] : 0;
    int run = base;
    for (int i = s0; i < s1; ++i) { indptr[i] = run; run += deg[i]; }
    if (s1 == N_ && s0 < N_) indptr[N_] = run;
}

__global__ void k_fill(const int* __restrict__ bond, const int* __restrict__ indptr,
                       int* __restrict__ cursor, int* __restrict__ adj) {
    int e = blockIdx.x * 256 + threadIdx.x;
    if (e < E_) {
        int s = bond[2 * e], d = bond[2 * e + 1];
        int ps = indptr[s] + atomicAdd(&cursor[s], 1);
        adj[ps] = (e << 1);        // node is src -> sign -
        int pd = indptr[d] + atomicAdd(&cursor[d], 1);
        adj[pd] = (e << 1) | 1;    // node is dst -> sign +
    }
}

__global__ void k_temb(const float* __restrict__ tv,
                       const float* __restrict__ W1, const float* __restrict__ b1,
                       const float* __restrict__ W2, const float* __restrict__ b2,
                       float* __restrict__ t_emb) {
    __shared__ float te[64];
    __shared__ float h1[128];
    int b = blockIdx.x;
    int tid = threadIdx.x;
    float tval = tv[b];
    if (tid < 32) {
        float fr = __expf((float)tid * (-logf(10000.f) / 31.f));
        float a = tval * fr;
        te[tid] = sinf(a);
        te[tid + 32] = cosf(a);
    }
    __syncthreads();
    float acc = b1[tid];
    for (int k = 0; k < 64; ++k) acc += te[k] * W1[k * 128 + tid];
    h1[tid] = silu_f(acc);
    __syncthreads();
    float acc2 = b2[tid];
    for (int k = 0; k < 128; ++k) acc2 += h1[k] * W2[k * 128 + tid];
    t_emb[b * 128 + tid] = acc2;
}

__global__ void k_embproj(const float* __restrict__ emb, const float* __restrict__ W,
                          const float* __restrict__ bias, float* __restrict__ outp) {
    int tid = threadIdx.x;       // 512 threads
    int a = tid >> 7, j = tid & 127;
    float acc = bias[j];
    for (int k = 0; k < 128; ++k) acc += emb[a * 128 + k] * W[k * 128 + j];
    outp[a * 128 + j] = acc;
}

__global__ void k_hinit(const int* __restrict__ at, const float* __restrict__ embp,
                        const float* __restrict__ temb, float* __restrict__ h) {
    size_t idx4 = (size_t)blockIdx.x * 256 + threadIdx.x;   // over B*N*H/4
    size_t e0 = idx4 * 4;
    int j = (int)(e0 % H_);
    size_t bn = e0 / H_;
    int n = (int)(bn % N_);
    int b = (int)(bn / N_);
    int a = at[n];
    float4 ep = *(const float4*)(embp + a * H_ + j);
    float4 tv = *(const float4*)(temb + b * H_ + j);
    ((float4*)h)[idx4] = make_float4(ep.x + tv.x, ep.y + tv.y, ep.z + tv.z, ep.w + tv.w);
}

__global__ void k_xcopy(const float* __restrict__ x, float* __restrict__ xb) {
    int i = blockIdx.x * 256 + threadIdx.x;  // 480000 exact
    xb[i] = x[i];
}

// ---------------- per-layer kernels ----------------

#define EPB 16

__global__ __launch_bounds__(256) void k_edge(
    const float* __restrict__ h, const float* __restrict__ xcur,
    const int* __restrict__ bond,
    const float* __restrict__ Wm1, const float* __restrict__ bm1,
    const float* __restrict__ Wm2, const float* __restrict__ bm2,
    const float* __restrict__ Wc1, const float* __restrict__ bc1,
    const float* __restrict__ Wc2,
    float* __restrict__ m_out, float* __restrict__ cw_out) {
    __shared__ float msg[EPB][260];
    __shared__ float buf1[EPB][132];
    __shared__ float buf2[EPB][132];
    int tid = threadIdx.x;
    int i = tid >> 4, lane = tid & 15;
    int be = blockIdx.x * EPB + i;
    int b = be / E_;
    int e = be - b * E_;
    int s = bond[2 * e], d = bond[2 * e + 1];
    const float4* hs4 = (const float4*)(h + ((size_t)(b * N_) + s) * H_);
    const float4* hd4 = (const float4*)(h + ((size_t)(b * N_) + d) * H_);
    float4 a0 = hs4[lane * 2], a1 = hs4[lane * 2 + 1];
    float4 c0 = hd4[lane * 2], c1v = hd4[lane * 2 + 1];
    *(float4*)&msg[i][lane * 8] = a0;
    *(float4*)&msg[i][lane * 8 + 4] = a1;
    *(float4*)&msg[i][128 + lane * 8] = c0;
    *(float4*)&msg[i][128 + lane * 8 + 4] = c1v;
    if (lane == 0) {
        const float* xs = xcur + ((size_t)(b * N_) + s) * 3;
        const float* xd = xcur + ((size_t)(b * N_) + d) * 3;
        float dx = xd[0] - xs[0], dy = xd[1] - xs[1], dz = xd[2] - xs[2];
        msg[i][256] = sqrtf(dx * dx + dy * dy + dz * dz);
    }
    __syncthreads();

    int ci = lane;
    float acc[8];
    // ---- GEMM1: msg(257) @ Wm1 -> silu
    {
        const float4* bv = (const float4*)bm1;
        float4 t0 = bv[ci * 2], t1 = bv[ci * 2 + 1];
        acc[0] = t0.x; acc[1] = t0.y; acc[2] = t0.z; acc[3] = t0.w;
        acc[4] = t1.x; acc[5] = t1.y; acc[6] = t1.z; acc[7] = t1.w;
        const float4* Wv = (const float4*)Wm1;
        #pragma unroll 4
        for (int k = 0; k < 257; ++k) {
            float sv = msg[i][k];
            float4 w0 = Wv[k * 32 + ci * 2];
            float4 w1 = Wv[k * 32 + ci * 2 + 1];
            acc[0] += sv * w0.x; acc[1] += sv * w0.y; acc[2] += sv * w0.z; acc[3] += sv * w0.w;
            acc[4] += sv * w1.x; acc[5] += sv * w1.y; acc[6] += sv * w1.z; acc[7] += sv * w1.w;
        }
    }
    #pragma unroll
    for (int q = 0; q < 8; ++q) acc[q] = silu_f(acc[q]);
    *(float4*)&buf1[i][ci * 8] = make_float4(acc[0], acc[1], acc[2], acc[3]);
    *(float4*)&buf1[i][ci * 8 + 4] = make_float4(acc[4], acc[5], acc[6], acc[7]);
    __syncthreads();

    // ---- GEMM2: m1(128) @ Wm2 -> silu -> m
    {
        const float4* bv = (const float4*)bm2;
        float4 t0 = bv[ci * 2], t1 = bv[ci * 2 + 1];
        acc[0] = t0.x; acc[1] = t0.y; acc[2] = t0.z; acc[3] = t0.w;
        acc[4] = t1.x; acc[5] = t1.y; acc[6] = t1.z; acc[7] = t1.w;
        const float4* Wv = (const float4*)Wm2;
        #pragma unroll 4
        for (int k = 0; k < 128; ++k) {
            float sv = buf1[i][k];
            float4 w0 = Wv[k * 32 + ci * 2];
            float4 w1 = Wv[k * 32 + ci * 2 + 1];
            acc[0] += sv * w0.x; acc[1] += sv * w0.y; acc[2] += sv * w0.z; acc[3] += sv * w0.w;
            acc[4] += sv * w1.x; acc[5] += sv * w1.y; acc[6] += sv * w1.z; acc[7] += sv * w1.w;
        }
    }
    #pragma unroll
    for (int q = 0; q < 8; ++q) acc[q] = silu_f(acc[q]);
    *(float4*)&buf2[i][ci * 8] = make_float4(acc[0], acc[1], acc[2], acc[3]);
    *(float4*)&buf2[i][ci * 8 + 4] = make_float4(acc[4], acc[5], acc[6], acc[7]);
    {
        float4* mo = (float4*)(m_out + (size_t)be * H_);
        mo[ci * 2] = make_float4(acc[0], acc[1], acc[2], acc[3]);
        mo[ci * 2 + 1] = make_float4(acc[4], acc[5], acc[6], acc[7]);
    }
    __syncthreads();

    // ---- GEMM3: cw = silu(m @ Wc1 + bc1) @ Wc2
    {
        const float4* bv = (const float4*)bc1;
        float4 t0 = bv[ci * 2], t1 = bv[ci * 2 + 1];
        acc[0] = t0.x; acc[1] = t0.y; acc[2] = t0.z; acc[3] = t0.w;
        acc[4] = t1.x; acc[5] = t1.y; acc[6] = t1.z; acc[7] = t1.w;
        const float4* Wv = (const float4*)Wc1;
        #pragma unroll 4
        for (int k = 0; k < 128; ++k) {
            float sv = buf2[i][k];
            float4 w0 = Wv[k * 32 + ci * 2];
            float4 w1 = Wv[k * 32 + ci * 2 + 1];
            acc[0] += sv * w0.x; acc[1] += sv * w0.y; acc[2] += sv * w0.z; acc[3] += sv * w0.w;
            acc[4] += sv * w1.x; acc[5] += sv * w1.y; acc[6] += sv * w1.z; acc[7] += sv * w1.w;
        }
    }
    float partial = 0.f;
    #pragma unroll
    for (int q = 0; q < 8; ++q) partial += silu_f(acc[q]) * Wc2[ci * 8 + q];
    buf1[i][ci] = partial;
    __syncthreads();
    if (tid < EPB) {
        float sum = 0.f;
        #pragma unroll
        for (int c = 0; c < 16; ++c) sum += buf1[tid][c];
        cw_out[blockIdx.x * EPB + tid] = sum;
    }
}

__global__ void k_coord(const float* __restrict__ xcur, float* __restrict__ xnext,
                        const float* __restrict__ cw, const int* __restrict__ bond,
                        const int* __restrict__ indptr, const int* __restrict__ adj) {
    int idx = blockIdx.x * 256 + threadIdx.x;   // B*N exact
    int b = idx / N_;
    int n = idx - b * N_;
    const float* xb = xcur + (size_t)b * N_ * 3;
    int p0 = indptr[n], p1 = indptr[n + 1];
    float ax = 0.f, ay = 0.f, az = 0.f;
    for (int p = p0; p < p1; ++p) {
        int a = adj[p];
        int e = a >> 1;
        float sgn = (a & 1) ? 1.f : -1.f;
        int s = bond[2 * e], d = bond[2 * e + 1];
        float dx = xb[d * 3 + 0] - xb[s * 3 + 0];
        float dy = xb[d * 3 + 1] - xb[s * 3 + 1];
        float dz = xb[d * 3 + 2] - xb[s * 3 + 2];
        float dist = sqrtf(dx * dx + dy * dy + dz * dz);
        float w = cw[(size_t)b * E_ + e] * sgn / (dist + 1e-8f);
        ax += dx * w; ay += dy * w; az += dz * w;
    }
    float cnt = (float)max(p1 - p0, 1);
    xnext[(size_t)idx * 3 + 0] = xb[n * 3 + 0] + ax / cnt;
    xnext[(size_t)idx * 3 + 1] = xb[n * 3 + 1] + ay / cnt;
    xnext[(size_t)idx * 3 + 2] = xb[n * 3 + 2] + az / cnt;
}

#define NPB 16

__global__ __launch_bounds__(256) void k_node(
    float* __restrict__ h, const float* __restrict__ m,
    const int* __restrict__ indptr, const int* __restrict__ adj,
    const float* __restrict__ Wn1, const float* __restrict__ bn1,
    const float* __restrict__ Wn2, const float* __restrict__ bn2) {
    __shared__ float hs[NPB][132];
    __shared__ float ag[NPB][132];
    __shared__ float us[NPB][132];
    int tid = threadIdx.x;
    int i = tid >> 4, lane = tid & 15;
    int be = blockIdx.x * NPB + i;      // b*N + n
    int b = be / N_;
    int n = be - b * N_;
    float* hrow = h + (size_t)be * H_;
    float4 h0 = ((const float4*)hrow)[lane * 2];
    float4 h1v = ((const float4*)hrow)[lane * 2 + 1];
    *(float4*)&hs[i][lane * 8] = h0;
    *(float4*)&hs[i][lane * 8 + 4] = h1v;
    float agr[8] = {0, 0, 0, 0, 0, 0, 0, 0};
    int p0 = indptr[n], p1 = indptr[n + 1];
    for (int p = p0; p < p1; ++p) {
        int e = adj[p] >> 1;
        const float4* mp = (const float4*)(m + ((size_t)(b * E_) + e) * H_);
        float4 m0 = mp[lane * 2], m1 = mp[lane * 2 + 1];
        agr[0] += m0.x; agr[1] += m0.y; agr[2] += m0.z; agr[3] += m0.w;
        agr[4] += m1.x; agr[5] += m1.y; agr[6] += m1.z; agr[7] += m1.w;
    }
    *(float4*)&ag[i][lane * 8] = make_float4(agr[0], agr[1], agr[2], agr[3]);
    *(float4*)&ag[i][lane * 8 + 4] = make_float4(agr[4], agr[5], agr[6], agr[7]);
    __syncthreads();

    int ci = lane;
    float acc[8];
    {
        const float4* bv = (const float4*)bn1;
        float4 t0 = bv[ci * 2], t1 = bv[ci * 2 + 1];
        acc[0] = t0.x; acc[1] = t0.y; acc[2] = t0.z; acc[3] = t0.w;
        acc[4] = t1.x; acc[5] = t1.y; acc[6] = t1.z; acc[7] = t1.w;
        const float4* Wv = (const float4*)Wn1;
        #pragma unroll 4
        for (int k = 0; k < 128; ++k) {
            float sv = hs[i][k];
            float4 w0 = Wv[k * 32 + ci * 2];
            float4 w1 = Wv[k * 32 + ci * 2 + 1];
            acc[0] += sv * w0.x; acc[1] += sv * w0.y; acc[2] += sv * w0.z; acc[3] += sv * w0.w;
            acc[4] += sv * w1.x; acc[5] += sv * w1.y; acc[6] += sv * w1.z; acc[7] += sv * w1.w;
        }
        #pragma unroll 4
        for (int k = 0; k < 128; ++k) {
            float sv = ag[i][k];
            float4 w0 = Wv[(k + 128) * 32 + ci * 2];
            float4 w1 = Wv[(k + 128) * 32 + ci * 2 + 1];
            acc[0] += sv * w0.x; acc[1] += sv * w0.y; acc[2] += sv * w0.z; acc[3] += sv * w0.w;
            acc[4] += sv * w1.x; acc[5] += sv * w1.y; acc[6] += sv * w1.z; acc[7] += sv * w1.w;
        }
    }
    #pragma unroll
    for (int q = 0; q < 8; ++q) acc[q] = silu_f(acc[q]);
    *(float4*)&us[i][ci * 8] = make_float4(acc[0], acc[1], acc[2], acc[3]);
    *(float4*)&us[i][ci * 8 + 4] = make_float4(acc[4], acc[5], acc[6], acc[7]);
    __syncthreads();

    {
        const float4* bv = (const float4*)bn2;
        float4 t0 = bv[ci * 2], t1 = bv[ci * 2 + 1];
        acc[0] = t0.x; acc[1] = t0.y; acc[2] = t0.z; acc[3] = t0.w;
        acc[4] = t1.x; acc[5] = t1.y; acc[6] = t1.z; acc[7] = t1.w;
        const float4* Wv = (const float4*)Wn2;
        #pragma unroll 4
        for (int k = 0; k < 128; ++k) {
            float sv = us[i][k];
            float4 w0 = Wv[k * 32 + ci * 2];
            float4 w1 = Wv[k * 32 + ci * 2 + 1];
            acc[0] += sv * w0.x; acc[1] += sv * w0.y; acc[2] += sv * w0.z; acc[3] += sv * w0.w;
            acc[4] += sv * w1.x; acc[5] += sv * w1.y; acc[6] += sv * w1.z; acc[7] += sv * w1.w;
        }
    }
    float4 o0 = make_float4(hs[i][ci * 8 + 0] + acc[0], hs[i][ci * 8 + 1] + acc[1],
                            hs[i][ci * 8 + 2] + acc[2], hs[i][ci * 8 + 3] + acc[3]);
    float4 o1 = make_float4(hs[i][ci * 8 + 4] + acc[4], hs[i][ci * 8 + 5] + acc[5],
                            hs[i][ci * 8 + 6] + acc[6], hs[i][ci * 8 + 7] + acc[7]);
    ((float4*)hrow)[ci * 2] = o0;
    ((float4*)hrow)[ci * 2 + 1] = o1;
}

__global__ __launch_bounds__(256) void k_out(
    const float* __restrict__ h, const float* __restrict__ xfin, const float* __restrict__ xorig,
    const float* __restrict__ Wo1, const float* __restrict__ bo1,
    const float* __restrict__ Wo2, const float* __restrict__ bo2,
    float* __restrict__ out) {
    __shared__ float hs[NPB][132];
    __shared__ float red[NPB][48];
    int tid = threadIdx.x;
    int i = tid >> 4, lane = tid & 15;
    int be = blockIdx.x * NPB + i;
    const float* hrow = h + (size_t)be * H_;
    float4 h0 = ((const float4*)hrow)[lane * 2];
    float4 h1v = ((const float4*)hrow)[lane * 2 + 1];
    *(float4*)&hs[i][lane * 8] = h0;
    *(float4*)&hs[i][lane * 8 + 4] = h1v;
    __syncthreads();

    int ci = lane;
    float acc[8];
    {
        const float4* bv = (const float4*)bo1;
        float4 t0 = bv[ci * 2], t1 = bv[ci * 2 + 1];
        acc[0] = t0.x; acc[1] = t0.y; acc[2] = t0.z; acc[3] = t0.w;
        acc[4] = t1.x; acc[5] = t1.y; acc[6] = t1.z; acc[7] = t1.w;
        const float4* Wv = (const float4*)Wo1;
        #pragma unroll 4
        for (int k = 0; k < 128; ++k) {
            float sv = hs[i][k];
            float4 w0 = Wv[k * 32 + ci * 2];
            float4 w1 = Wv[k * 32 + ci * 2 + 1];
            acc[0] += sv * w0.x; acc[1] += sv * w0.y; acc[2] += sv * w0.z; acc[3] += sv * w0.w;
            acc[4] += sv * w1.x; acc[5] += sv * w1.y; acc[6] += sv * w1.z; acc[7] += sv * w1.w;
        }
    }
    float p0 = 0.f, p1 = 0.f, p2 = 0.f;
    #pragma unroll
    for (int q = 0; q < 8; ++q) {
        float u = silu_f(acc[q]);
        int col = ci * 8 + q;
        p0 += u * Wo2[col * 3 + 0];
        p1 += u * Wo2[col * 3 + 1];
        p2 += u * Wo2[col * 3 + 2];
    }
    red[i][lane * 3 + 0] = p0;
    red[i][lane * 3 + 1] = p1;
    red[i][lane * 3 + 2] = p2;
    __syncthreads();
    if (tid < NPB * 3) {
        int ii = tid / 3, j = tid - ii * 3;
        float s2 = 0.f;
        #pragma unroll
        for (int c = 0; c < 16; ++c) s2 += red[ii][c * 3 + j];
        int bee = blockIdx.x * NPB + ii;
        out[(size_t)bee * 3 + j] = s2 + bo2[j] + xfin[(size_t)bee * 3 + j] - xorig[(size_t)bee * 3 + j];
    }
}

// ---------------- launcher ----------------

extern "C" void kernel_launch(void* const* d_in, const int* in_sizes, int n_in,
                              void* d_out, int out_size, void* d_ws, size_t ws_size,
                              hipStream_t stream) {
    const float* x = (const float*)d_in[0];
    const float* t = (const float*)d_in[1];
    const int* atom_types = (const int*)d_in[2];
    const int* bond = (const int*)d_in[3];
    const float* emb_table = (const float*)d_in[4];
    const float* W_t1 = (const float*)d_in[5];
    const float* b_t1 = (const float*)d_in[6];
    const float* W_t2 = (const float*)d_in[7];
    const float* b_t2 = (const float*)d_in[8];
    const float* W_node = (const float*)d_in[9];
    const float* b_node = (const float*)d_in[10];
    const float* Wm1 = (const float*)d_in[11];
    const float* bm1 = (const float*)d_in[12];
    const float* Wm2 = (const float*)d_in[13];
    const float* bm2 = (const float*)d_in[14];
    const float* Wn1 = (const float*)d_in[15];
    const float* bn1 = (const float*)d_in[16];
    const float* Wn2 = (const float*)d_in[17];
    const float* bn2 = (const float*)d_in[18];
    const float* Wc1 = (const float*)d_in[19];
    const float* bc1 = (const float*)d_in[20];
    const float* Wc2 = (const float*)d_in[21];
    const float* W_o1 = (const float*)d_in[22];
    const float* b_o1 = (const float*)d_in[23];
    const float* W_o2 = (const float*)d_in[24];
    const float* b_o2 = (const float*)d_in[25];
    float* out = (float*)d_out;

    char* p = (char*)d_ws;
    auto alloc = [&](size_t bytes) -> void* {
        void* r = (void*)p;
        p += (bytes + 255) & ~(size_t)255;
        return r;
    };
    float* t_emb = (float*)alloc((size_t)B_ * H_ * 4);
    float* emb_proj = (float*)alloc((size_t)A_ * H_ * 4);
    int* deg = (int*)alloc((size_t)N_ * 4);
    int* indptr = (int*)alloc((size_t)(N_ + 1) * 4);
    int* cursor = (int*)alloc((size_t)N_ * 4);
    int* adj = (int*)alloc((size_t)2 * E_ * 4);
    float* xb0 = (float*)alloc((size_t)B_ * N_ * 3 * 4);
    float* xb1 = (float*)alloc((size_t)B_ * N_ * 3 * 4);
    float* cw = (float*)alloc((size_t)B_ * E_ * 4);
    float* h = (float*)alloc((size_t)B_ * N_ * H_ * 4);
    float* m = (float*)alloc((size_t)B_ * E_ * H_ * 4);

    k_zero<<<(N_ + 255) / 256, 256, 0, stream>>>(deg, cursor);
    k_deg<<<(E_ + 255) / 256, 256, 0, stream>>>(bond, deg);
    k_scan<<<1, 1024, 0, stream>>>(deg, indptr);
    k_fill<<<(E_ + 255) / 256, 256, 0, stream>>>(bond, indptr, cursor, adj);
    k_temb<<<B_, 128, 0, stream>>>(t, W_t1, b_t1, W_t2, b_t2, t_emb);
    k_embproj<<<1, 512, 0, stream>>>(emb_table, W_node, b_node, emb_proj);
    k_hinit<<<(B_ * N_ * H_ / 4) / 256, 256, 0, stream>>>(atom_types, emb_proj, t_emb, h);
    k_xcopy<<<(B_ * N_ * 3) / 256, 256, 0, stream>>>(x, xb0);

    float* xc = xb0;
    float* xn = xb1;
    for (int l = 0; l < L_; ++l) {
        k_edge<<<(B_ * E_) / EPB, 256, 0, stream>>>(
            h, xc, bond,
            Wm1 + (size_t)l * 257 * H_, bm1 + l * H_,
            Wm2 + (size_t)l * H_ * H_, bm2 + l * H_,
            Wc1 + (size_t)l * H_ * H_, bc1 + l * H_,
            Wc2 + (size_t)l * H_, m, cw);
        k_coord<<<(B_ * N_) / 256, 256, 0, stream>>>(xc, xn, cw, bond, indptr, adj);
        k_node<<<(B_ * N_) / NPB, 256, 0, stream>>>(
            h, m, indptr, adj,
            Wn1 + (size_t)l * 2 * H_ * H_, bn1 + l * H_,
            Wn2 + (size_t)l * H_ * H_, bn2 + l * H_);
        float* tmp = xc; xc = xn; xn = tmp;
    }
    k_out<<<(B_ * N_) / NPB, 256, 0, stream>>>(h, xc, x, W_o1, b_o1, W_o2, b_o2, out);
}

// Round 3
// 4133.202 us; speedup vs baseline: 3.1669x; 3.1669x over previous
//
#include <hip/hip_runtime.h>
#include <math.h>

#define B_ 8
#define N_ 20000
#define E_ 40000
#define H_ 128
#define L_ 4
#define A_ 4
#define TS 132   // LDS row stride for 64x128 tiles (128+4: 4-row phase = 2-way, free)
#define MS 260   // LDS row stride for 64x256 edge tile (256+4: same phase property)

__device__ __forceinline__ float silu_f(float x) { return x / (1.f + __expf(-x)); }

// ---------------- setup kernels ----------------

__global__ void k_zero(int* __restrict__ deg, int* __restrict__ cursor) {
    int i = blockIdx.x * 256 + threadIdx.x;
    if (i < N_) { deg[i] = 0; cursor[i] = 0; }
}

__global__ void k_deg(const int* __restrict__ bond, int* __restrict__ deg) {
    int e = blockIdx.x * 256 + threadIdx.x;
    if (e < E_) {
        atomicAdd(&deg[bond[2 * e]], 1);
        atomicAdd(&deg[bond[2 * e + 1]], 1);
    }
}

__global__ void k_scan(const int* __restrict__ deg, int* __restrict__ indptr) {
    __shared__ int sums[1024];
    const int CH = (N_ + 1023) / 1024;  // 20
    int t = threadIdx.x;
    int s0 = t * CH;
    int s1 = min(s0 + CH, N_);
    int s = 0;
    for (int i = s0; i < s1; ++i) s += deg[i];
    sums[t] = s;
    __syncthreads();
    for (int off = 1; off < 1024; off <<= 1) {
        int v = (t >= off) ? sums[t - off] : 0;
        __syncthreads();
        sums[t] += v;
        __syncthreads();
    }
    int base = (t > 0) ? sums[t - 1] : 0;
    int run = base;
    for (int i = s0; i < s1; ++i) { indptr[i] = run; run += deg[i]; }
    if (s1 == N_ && s0 < N_) indptr[N_] = run;
}

__global__ void k_fill(const int* __restrict__ bond, const int* __restrict__ indptr,
                       int* __restrict__ cursor, int* __restrict__ adj) {
    int e = blockIdx.x * 256 + threadIdx.x;
    if (e < E_) {
        int s = bond[2 * e], d = bond[2 * e + 1];
        int ps = indptr[s] + atomicAdd(&cursor[s], 1);
        adj[ps] = (e << 1);        // node is src -> sign -
        int pd = indptr[d] + atomicAdd(&cursor[d], 1);
        adj[pd] = (e << 1) | 1;    // node is dst -> sign +
    }
}

__global__ void k_temb(const float* __restrict__ tv,
                       const float* __restrict__ W1, const float* __restrict__ b1,
                       const float* __restrict__ W2, const float* __restrict__ b2,
                       float* __restrict__ t_emb) {
    __shared__ float te[64];
    __shared__ float h1[128];
    int b = blockIdx.x;
    int tid = threadIdx.x;
    float tval = tv[b];
    if (tid < 32) {
        float fr = __expf((float)tid * (-logf(10000.f) / 31.f));
        float a = tval * fr;
        te[tid] = sinf(a);
        te[tid + 32] = cosf(a);
    }
    __syncthreads();
    float acc = b1[tid];
    for (int k = 0; k < 64; ++k) acc += te[k] * W1[k * 128 + tid];
    h1[tid] = silu_f(acc);
    __syncthreads();
    float acc2 = b2[tid];
    for (int k = 0; k < 128; ++k) acc2 += h1[k] * W2[k * 128 + tid];
    t_emb[b * 128 + tid] = acc2;
}

__global__ void k_embproj(const float* __restrict__ emb, const float* __restrict__ W,
                          const float* __restrict__ bias, float* __restrict__ outp) {
    int tid = threadIdx.x;       // 512 threads
    int a = tid >> 7, j = tid & 127;
    float acc = bias[j];
    for (int k = 0; k < 128; ++k) acc += emb[a * 128 + k] * W[k * 128 + j];
    outp[a * 128 + j] = acc;
}

__global__ void k_hinit(const int* __restrict__ at, const float* __restrict__ embp,
                        const float* __restrict__ temb, float* __restrict__ h) {
    size_t idx4 = (size_t)blockIdx.x * 256 + threadIdx.x;   // over B*N*H/4
    size_t e0 = idx4 * 4;
    int j = (int)(e0 % H_);
    size_t bn = e0 / H_;
    int n = (int)(bn % N_);
    int b = (int)(bn / N_);
    int a = at[n];
    float4 ep = *(const float4*)(embp + a * H_ + j);
    float4 tv = *(const float4*)(temb + b * H_ + j);
    ((float4*)h)[idx4] = make_float4(ep.x + tv.x, ep.y + tv.y, ep.z + tv.z, ep.w + tv.w);
}

__global__ void k_xcopy(const float* __restrict__ x, float* __restrict__ xb) {
    int i = blockIdx.x * 256 + threadIdx.x;  // 480000 exact
    xb[i] = x[i];
}

// ---------------- tiled fp32 GEMM core ----------------
// A tile in LDS (row stride STRIDE). W: K x 128 global row-major.
// Thread (r4=(tid>>4)*4, c=tid&15) accumulates rows r4..r4+3, cols c*8..c*8+7.
template <int STRIDE, int K>
__device__ __forceinline__ void gemm_t(const float* As, const float* __restrict__ W,
                                       float (&acc)[4][8], int r4, int c) {
    const float4* Wv = (const float4*)W;
    #pragma unroll 2
    for (int k = 0; k < K; k += 4) {
        float a[4][4];
        #pragma unroll
        for (int i = 0; i < 4; ++i)
            *(float4*)a[i] = *(const float4*)(As + (r4 + i) * STRIDE + k);
        #pragma unroll
        for (int kk = 0; kk < 4; ++kk) {
            float4 w0 = Wv[(k + kk) * 32 + c * 2];
            float4 w1 = Wv[(k + kk) * 32 + c * 2 + 1];
            #pragma unroll
            for (int i = 0; i < 4; ++i) {
                float av = a[i][kk];
                acc[i][0] += av * w0.x; acc[i][1] += av * w0.y;
                acc[i][2] += av * w0.z; acc[i][3] += av * w0.w;
                acc[i][4] += av * w1.x; acc[i][5] += av * w1.y;
                acc[i][6] += av * w1.z; acc[i][7] += av * w1.w;
            }
        }
    }
}

__device__ __forceinline__ void bias_init(float (&acc)[4][8], const float* __restrict__ bias, int c) {
    float4 b0 = ((const float4*)bias)[c * 2];
    float4 b1 = ((const float4*)bias)[c * 2 + 1];
    #pragma unroll
    for (int i = 0; i < 4; ++i) {
        acc[i][0] = b0.x; acc[i][1] = b0.y; acc[i][2] = b0.z; acc[i][3] = b0.w;
        acc[i][4] = b1.x; acc[i][5] = b1.y; acc[i][6] = b1.z; acc[i][7] = b1.w;
    }
}

// ---------------- per-layer kernels ----------------

// Edge pipeline, 64 edges/block:
//   msg[64][256] = [h_src | h_dst] gathered to LDS; dist folded into acc init.
//   m1 = silu(msg @ Wm1[0:256] + dist*Wm1[256] + bm1)   -> msg cols 0..127
//   m  = silu(m1 @ Wm2 + bm2)                           -> global + msg cols 128..255
//   cw = (silu(m @ Wc1 + bc1)) @ Wc2                    -> global
__global__ __launch_bounds__(256) void k_edge3(
    const float* __restrict__ h, const float* __restrict__ xcur,
    const int* __restrict__ bond,
    const float* __restrict__ Wm1, const float* __restrict__ bm1,
    const float* __restrict__ Wm2, const float* __restrict__ bm2,
    const float* __restrict__ Wc1, const float* __restrict__ bc1,
    const float* __restrict__ Wc2,
    float* __restrict__ m_out, float* __restrict__ cw_out) {
    __shared__ float msg[64 * MS];   // 66560 B
    __shared__ float ds[64];
    __shared__ float red[64 * 16];
    int tid = threadIdx.x;
    {
        int el = tid >> 2, q = tid & 3;
        int be = blockIdx.x * 64 + el;
        int b = be / E_, e = be - b * E_;
        int s = bond[2 * e], d = bond[2 * e + 1];
        const float4* hs4 = (const float4*)(h + ((size_t)b * N_ + s) * H_);
        const float4* hd4 = (const float4*)(h + ((size_t)b * N_ + d) * H_);
        #pragma unroll
        for (int j = 0; j < 8; ++j) {
            int f4 = j * 4 + q;
            *(float4*)(msg + el * MS + f4 * 4) = hs4[f4];
            *(float4*)(msg + el * MS + 128 + f4 * 4) = hd4[f4];
        }
        if (q == 0) {
            const float* xs = xcur + ((size_t)b * N_ + s) * 3;
            const float* xd = xcur + ((size_t)b * N_ + d) * 3;
            float dx = xd[0] - xs[0], dy = xd[1] - xs[1], dz = xd[2] - xs[2];
            ds[el] = sqrtf(dx * dx + dy * dy + dz * dz);
        }
    }
    __syncthreads();

    int r4 = (tid >> 4) * 4, c = tid & 15;
    size_t be0 = (size_t)blockIdx.x * 64;
    float acc[4][8];

    // ---- GEMM1: acc = bm1 + dist*wd + msg @ Wm1[0:256]
    {
        const float* wd = Wm1 + 256 * H_;
        float4 b0 = ((const float4*)bm1)[c * 2], b1v = ((const float4*)bm1)[c * 2 + 1];
        float4 w0 = ((const float4*)wd)[c * 2], w1 = ((const float4*)wd)[c * 2 + 1];
        #pragma unroll
        for (int i = 0; i < 4; ++i) {
            float di = ds[r4 + i];
            acc[i][0] = b0.x + di * w0.x; acc[i][1] = b0.y + di * w0.y;
            acc[i][2] = b0.z + di * w0.z; acc[i][3] = b0.w + di * w0.w;
            acc[i][4] = b1v.x + di * w1.x; acc[i][5] = b1v.y + di * w1.y;
            acc[i][6] = b1v.z + di * w1.z; acc[i][7] = b1v.w + di * w1.w;
        }
    }
    gemm_t<MS, 256>(msg, Wm1, acc, r4, c);
    #pragma unroll
    for (int i = 0; i < 4; ++i)
        #pragma unroll
        for (int j = 0; j < 8; ++j) acc[i][j] = silu_f(acc[i][j]);
    __syncthreads();   // all GEMM1 reads done
    #pragma unroll
    for (int i = 0; i < 4; ++i) {       // m1 -> msg cols 0..127
        *(float4*)(msg + (r4 + i) * MS + c * 8) = make_float4(acc[i][0], acc[i][1], acc[i][2], acc[i][3]);
        *(float4*)(msg + (r4 + i) * MS + c * 8 + 4) = make_float4(acc[i][4], acc[i][5], acc[i][6], acc[i][7]);
    }
    __syncthreads();

    // ---- GEMM2: m = silu(m1 @ Wm2 + bm2)
    bias_init(acc, bm2, c);
    gemm_t<MS, 128>(msg, Wm2, acc, r4, c);
    #pragma unroll
    for (int i = 0; i < 4; ++i)
        #pragma unroll
        for (int j = 0; j < 8; ++j) acc[i][j] = silu_f(acc[i][j]);
    #pragma unroll
    for (int i = 0; i < 4; ++i) {
        float4* mo = (float4*)(m_out + (be0 + r4 + i) * H_ + c * 8);
        mo[0] = make_float4(acc[i][0], acc[i][1], acc[i][2], acc[i][3]);
        mo[1] = make_float4(acc[i][4], acc[i][5], acc[i][6], acc[i][7]);
        // m -> msg cols 128..255 (no one reads this region during GEMM2)
        *(float4*)(msg + (r4 + i) * MS + 128 + c * 8) = make_float4(acc[i][0], acc[i][1], acc[i][2], acc[i][3]);
        *(float4*)(msg + (r4 + i) * MS + 128 + c * 8 + 4) = make_float4(acc[i][4], acc[i][5], acc[i][6], acc[i][7]);
    }
    __syncthreads();

    // ---- GEMM3: cw = silu(m @ Wc1 + bc1) @ Wc2
    bias_init(acc, bc1, c);
    gemm_t<MS, 128>(msg + 128, Wc1, acc, r4, c);
    const float* wc2c = Wc2 + c * 8;
    #pragma unroll
    for (int i = 0; i < 4; ++i) {
        float part = 0.f;
        #pragma unroll
        for (int j = 0; j < 8; ++j) part += silu_f(acc[i][j]) * wc2c[j];
        red[(r4 + i) * 16 + c] = part;
    }
    __syncthreads();
    if (tid < 64) {
        float s = 0.f;
        #pragma unroll
        for (int cc = 0; cc < 16; ++cc) s += red[tid * 16 + cc];
        cw_out[be0 + tid] = s;
    }
}

__global__ void k_coord(const float* __restrict__ xcur, float* __restrict__ xnext,
                        const float* __restrict__ cw, const int* __restrict__ bond,
                        const int* __restrict__ indptr, const int* __restrict__ adj) {
    int idx = blockIdx.x * 256 + threadIdx.x;   // B*N exact
    int b = idx / N_;
    int n = idx - b * N_;
    const float* xb = xcur + (size_t)b * N_ * 3;
    int p0 = indptr[n], p1 = indptr[n + 1];
    float ax = 0.f, ay = 0.f, az = 0.f;
    for (int p = p0; p < p1; ++p) {
        int a = adj[p];
        int e = a >> 1;
        float sgn = (a & 1) ? 1.f : -1.f;
        int s = bond[2 * e], d = bond[2 * e + 1];
        float dx = xb[d * 3 + 0] - xb[s * 3 + 0];
        float dy = xb[d * 3 + 1] - xb[s * 3 + 1];
        float dz = xb[d * 3 + 2] - xb[s * 3 + 2];
        float dist = sqrtf(dx * dx + dy * dy + dz * dz);
        float w = cw[(size_t)b * E_ + e] * sgn / (dist + 1e-8f);
        ax += dx * w; ay += dy * w; az += dz * w;
    }
    float cnt = (float)max(p1 - p0, 1);
    xnext[(size_t)idx * 3 + 0] = xb[n * 3 + 0] + ax / cnt;
    xnext[(size_t)idx * 3 + 1] = xb[n * 3 + 1] + ay / cnt;
    xnext[(size_t)idx * 3 + 2] = xb[n * 3 + 2] + az / cnt;
}

// agg gather; u = silu(h@Wn1a + agg@Wn1b + bn1); h += u@Wn2 + bn2
__global__ __launch_bounds__(256) void k_node2(
    float* __restrict__ h, const float* __restrict__ m,
    const int* __restrict__ indptr, const int* __restrict__ adj,
    const float* __restrict__ Wn1, const float* __restrict__ bn1,
    const float* __restrict__ Wn2, const float* __restrict__ bn2) {
    __shared__ float As[64 * TS];
    int tid = threadIdx.x;
    int nl = tid >> 2, q = tid & 3;
    int be = blockIdx.x * 64 + nl;   // b*N + n
    int b = be / N_, n = be - b * N_;
    // stage h tile
    {
        const float4* hr = (const float4*)(h + (size_t)be * H_);
        #pragma unroll
        for (int j = 0; j < 8; ++j) {
            int f4 = j * 4 + q;
            *(float4*)(As + nl * TS + f4 * 4) = hr[f4];
        }
    }
    __syncthreads();
    int r4 = (tid >> 4) * 4, c = tid & 15;
    float acc[4][8];
    bias_init(acc, bn1, c);
    gemm_t<TS, 128>(As, Wn1, acc, r4, c);    // + h @ Wn1a
    __syncthreads();                         // h tile reads done
    // overwrite As with agg gather
    {
        float4 ag[8];
        #pragma unroll
        for (int j = 0; j < 8; ++j) ag[j] = make_float4(0.f, 0.f, 0.f, 0.f);
        int p0 = indptr[n], p1 = indptr[n + 1];
        for (int p = p0; p < p1; ++p) {
            int e = adj[p] >> 1;
            const float4* mp = (const float4*)(m + ((size_t)b * E_ + e) * H_);
            #pragma unroll
            for (int j = 0; j < 8; ++j) {
                float4 v = mp[j * 4 + q];
                ag[j].x += v.x; ag[j].y += v.y; ag[j].z += v.z; ag[j].w += v.w;
            }
        }
        #pragma unroll
        for (int j = 0; j < 8; ++j)
            *(float4*)(As + nl * TS + (j * 4 + q) * 4) = ag[j];
    }
    __syncthreads();
    gemm_t<TS, 128>(As, Wn1 + 128 * H_, acc, r4, c); // + agg @ Wn1b
    #pragma unroll
    for (int i = 0; i < 4; ++i)
        #pragma unroll
        for (int j = 0; j < 8; ++j) acc[i][j] = silu_f(acc[i][j]);
    __syncthreads();                         // agg reads done
    #pragma unroll
    for (int i = 0; i < 4; ++i) {            // u -> As (in place)
        *(float4*)(As + (r4 + i) * TS + c * 8) = make_float4(acc[i][0], acc[i][1], acc[i][2], acc[i][3]);
        *(float4*)(As + (r4 + i) * TS + c * 8 + 4) = make_float4(acc[i][4], acc[i][5], acc[i][6], acc[i][7]);
    }
    __syncthreads();
    float acc2[4][8];
    bias_init(acc2, bn2, c);
    gemm_t<TS, 128>(As, Wn2, acc2, r4, c);
    // residual from global h + writeback
    #pragma unroll
    for (int i = 0; i < 4; ++i) {
        size_t row = (size_t)blockIdx.x * 64 + r4 + i;
        float4* hp = (float4*)(h + row * H_ + c * 8);
        float4 h0 = hp[0], h1 = hp[1];
        hp[0] = make_float4(h0.x + acc2[i][0], h0.y + acc2[i][1], h0.z + acc2[i][2], h0.w + acc2[i][3]);
        hp[1] = make_float4(h1.x + acc2[i][4], h1.y + acc2[i][5], h1.z + acc2[i][6], h1.w + acc2[i][7]);
    }
}

// out = silu(h@Wo1+bo1)@Wo2 + bo2 + (xfin - xorig)
__global__ __launch_bounds__(256) void k_out2(
    const float* __restrict__ h, const float* __restrict__ xfin, const float* __restrict__ xorig,
    const float* __restrict__ Wo1, const float* __restrict__ bo1,
    const float* __restrict__ Wo2, const float* __restrict__ bo2,
    float* __restrict__ out) {
    __shared__ float As[64 * TS];
    __shared__ float red[64 * 48];
    int tid = threadIdx.x;
    {
        int nl = tid >> 2, q = tid & 3;
        size_t row = (size_t)blockIdx.x * 64 + nl;
        const float4* hr = (const float4*)(h + row * H_);
        #pragma unroll
        for (int j = 0; j < 8; ++j) {
            int f4 = j * 4 + q;
            *(float4*)(As + nl * TS + f4 * 4) = hr[f4];
        }
    }
    __syncthreads();
    int r4 = (tid >> 4) * 4, c = tid & 15;
    float acc[4][8];
    bias_init(acc, bo1, c);
    gemm_t<TS, 128>(As, Wo1, acc, r4, c);
    #pragma unroll
    for (int i = 0; i < 4; ++i) {
        float p0 = 0.f, p1 = 0.f, p2 = 0.f;
        #pragma unroll
        for (int j = 0; j < 8; ++j) {
            float u = silu_f(acc[i][j]);
            int col = c * 8 + j;
            p0 += u * Wo2[col * 3 + 0];
            p1 += u * Wo2[col * 3 + 1];
            p2 += u * Wo2[col * 3 + 2];
        }
        red[(r4 + i) * 48 + c * 3 + 0] = p0;
        red[(r4 + i) * 48 + c * 3 + 1] = p1;
        red[(r4 + i) * 48 + c * 3 + 2] = p2;
    }
    __syncthreads();
    if (tid < 192) {
        int row = tid / 3, jj = tid - row * 3;
        float s = 0.f;
        #pragma unroll
        for (int cc = 0; cc < 16; ++cc) s += red[row * 48 + cc * 3 + jj];
        size_t grow = (size_t)blockIdx.x * 64 + row;
        out[grow * 3 + jj] = s + bo2[jj] + xfin[grow * 3 + jj] - xorig[grow * 3 + jj];
    }
}

// ---------------- launcher ----------------

extern "C" void kernel_launch(void* const* d_in, const int* in_sizes, int n_in,
                              void* d_out, int out_size, void* d_ws, size_t ws_size,
                              hipStream_t stream) {
    const float* x = (const float*)d_in[0];
    const float* t = (const float*)d_in[1];
    const int* atom_types = (const int*)d_in[2];
    const int* bond = (const int*)d_in[3];
    const float* emb_table = (const float*)d_in[4];
    const float* W_t1 = (const float*)d_in[5];
    const float* b_t1 = (const float*)d_in[6];
    const float* W_t2 = (const float*)d_in[7];
    const float* b_t2 = (const float*)d_in[8];
    const float* W_node = (const float*)d_in[9];
    const float* b_node = (const float*)d_in[10];
    const float* Wm1 = (const float*)d_in[11];
    const float* bm1 = (const float*)d_in[12];
    const float* Wm2 = (const float*)d_in[13];
    const float* bm2 = (const float*)d_in[14];
    const float* Wn1 = (const float*)d_in[15];
    const float* bn1 = (const float*)d_in[16];
    const float* Wn2 = (const float*)d_in[17];
    const float* bn2 = (const float*)d_in[18];
    const float* Wc1 = (const float*)d_in[19];
    const float* bc1 = (const float*)d_in[20];
    const float* Wc2 = (const float*)d_in[21];
    const float* W_o1 = (const float*)d_in[22];
    const float* b_o1 = (const float*)d_in[23];
    const float* W_o2 = (const float*)d_in[24];
    const float* b_o2 = (const float*)d_in[25];
    float* out = (float*)d_out;

    char* p = (char*)d_ws;
    auto alloc = [&](size_t bytes) -> void* {
        void* r = (void*)p;
        p += (bytes + 255) & ~(size_t)255;
        return r;
    };
    // Total ~252 MB — proven to fit ws_size in R1. (R2's +164 MB P/Q overflowed.)
    float* t_emb = (float*)alloc((size_t)B_ * H_ * 4);
    float* emb_proj = (float*)alloc((size_t)A_ * H_ * 4);
    int* deg = (int*)alloc((size_t)N_ * 4);
    int* indptr = (int*)alloc((size_t)(N_ + 1) * 4);
    int* cursor = (int*)alloc((size_t)N_ * 4);
    int* adj = (int*)alloc((size_t)2 * E_ * 4);
    float* xb0 = (float*)alloc((size_t)B_ * N_ * 3 * 4);
    float* xb1 = (float*)alloc((size_t)B_ * N_ * 3 * 4);
    float* cw = (float*)alloc((size_t)B_ * E_ * 4);
    float* h = (float*)alloc((size_t)B_ * N_ * H_ * 4);
    float* m = (float*)alloc((size_t)B_ * E_ * H_ * 4);

    k_zero<<<(N_ + 255) / 256, 256, 0, stream>>>(deg, cursor);
    k_deg<<<(E_ + 255) / 256, 256, 0, stream>>>(bond, deg);
    k_scan<<<1, 1024, 0, stream>>>(deg, indptr);
    k_fill<<<(E_ + 255) / 256, 256, 0, stream>>>(bond, indptr, cursor, adj);
    k_temb<<<B_, 128, 0, stream>>>(t, W_t1, b_t1, W_t2, b_t2, t_emb);
    k_embproj<<<1, 512, 0, stream>>>(emb_table, W_node, b_node, emb_proj);
    k_hinit<<<(B_ * N_ * H_ / 4) / 256, 256, 0, stream>>>(atom_types, emb_proj, t_emb, h);
    k_xcopy<<<(B_ * N_ * 3) / 256, 256, 0, stream>>>(x, xb0);

    float* xc = xb0;
    float* xn = xb1;
    for (int l = 0; l < L_; ++l) {
        k_edge3<<<(B_ * E_) / 64, 256, 0, stream>>>(
            h, xc, bond,
            Wm1 + (size_t)l * 257 * H_, bm1 + l * H_,
            Wm2 + (size_t)l * H_ * H_, bm2 + l * H_,
            Wc1 + (size_t)l * H_ * H_, bc1 + l * H_,
            Wc2 + (size_t)l * H_, m, cw);
        k_coord<<<(B_ * N_) / 256, 256, 0, stream>>>(xc, xn, cw, bond, indptr, adj);
        k_node2<<<(B_ * N_) / 64, 256, 0, stream>>>(
            h, m, indptr, adj,
            Wn1 + (size_t)l * 2 * H_ * H_, bn1 + l * H_,
            Wn2 + (size_t)l * H_ * H_, bn2 + l * H_);
        float* tmp = xc; xc = xn; xn = tmp;
    }
    k_out2<<<(B_ * N_) / 64, 256, 0, stream>>>(h, xc, x, W_o1, b_o1, W_o2, b_o2, out);
}

// Round 4
// 1253.301 us; speedup vs baseline: 10.4441x; 3.2979x over previous
//
#include <hip/hip_runtime.h>
#include <math.h>

#define B_ 8
#define N_ 20000
#define E_ 40000
#define H_ 128
#define L_ 4
#define A_ 4
#define TS 132    // fp32 LDS row stride (k_out2)
#define ERS 264   // fp16 LDS row stride, edge kernel (256+8)
#define NRS 136   // fp16 LDS row stride, node kernel (128+8)

typedef _Float16 f16x8 __attribute__((ext_vector_type(8)));
typedef _Float16 f16x4v __attribute__((ext_vector_type(4)));
typedef float f32x4 __attribute__((ext_vector_type(4)));

__device__ __forceinline__ float silu_f(float x) { return x / (1.f + __expf(-x)); }

// ---------------- setup kernels ----------------

__global__ void k_zero(int* __restrict__ deg, int* __restrict__ cursor) {
    int i = blockIdx.x * 256 + threadIdx.x;
    if (i < N_) { deg[i] = 0; cursor[i] = 0; }
}

__global__ void k_deg(const int* __restrict__ bond, int* __restrict__ deg) {
    int e = blockIdx.x * 256 + threadIdx.x;
    if (e < E_) {
        atomicAdd(&deg[bond[2 * e]], 1);
        atomicAdd(&deg[bond[2 * e + 1]], 1);
    }
}

__global__ void k_scan(const int* __restrict__ deg, int* __restrict__ indptr) {
    __shared__ int sums[1024];
    const int CH = (N_ + 1023) / 1024;  // 20
    int t = threadIdx.x;
    int s0 = t * CH;
    int s1 = min(s0 + CH, N_);
    int s = 0;
    for (int i = s0; i < s1; ++i) s += deg[i];
    sums[t] = s;
    __syncthreads();
    for (int off = 1; off < 1024; off <<= 1) {
        int v = (t >= off) ? sums[t - off] : 0;
        __syncthreads();
        sums[t] += v;
        __syncthreads();
    }
    int base = (t > 0) ? sums[t - 1] : 0;
    int run = base;
    for (int i = s0; i < s1; ++i) { indptr[i] = run; run += deg[i]; }
    if (s1 == N_ && s0 < N_) indptr[N_] = run;
}

__global__ void k_fill(const int* __restrict__ bond, const int* __restrict__ indptr,
                       int* __restrict__ cursor, int* __restrict__ adj) {
    int e = blockIdx.x * 256 + threadIdx.x;
    if (e < E_) {
        int s = bond[2 * e], d = bond[2 * e + 1];
        int ps = indptr[s] + atomicAdd(&cursor[s], 1);
        adj[ps] = (e << 1);        // node is src -> sign -
        int pd = indptr[d] + atomicAdd(&cursor[d], 1);
        adj[pd] = (e << 1) | 1;    // node is dst -> sign +
    }
}

// Convert W[K][128] fp32 -> B-fragment-layout fp16 for mfma_f32_16x16x32_f16:
// Wf[((kt*8 + nt)*64 + lane)*8 + j] = W[kt*32 + (lane>>4)*8 + j][nt*16 + (lane&15)]
__global__ void k_wprep(const float* __restrict__ W, _Float16* __restrict__ Wf, int K) {
    int idx = blockIdx.x * 256 + threadIdx.x;
    if (idx >= K * 128) return;
    int j = idx & 7, lane = (idx >> 3) & 63, nt = (idx >> 9) & 7, kt = idx >> 12;
    int k = kt * 32 + (lane >> 4) * 8 + j;
    int n = nt * 16 + (lane & 15);
    Wf[idx] = (_Float16)W[k * 128 + n];
}

__global__ void k_temb(const float* __restrict__ tv,
                       const float* __restrict__ W1, const float* __restrict__ b1,
                       const float* __restrict__ W2, const float* __restrict__ b2,
                       float* __restrict__ t_emb) {
    __shared__ float te[64];
    __shared__ float h1[128];
    int b = blockIdx.x;
    int tid = threadIdx.x;
    float tval = tv[b];
    if (tid < 32) {
        float fr = __expf((float)tid * (-logf(10000.f) / 31.f));
        float a = tval * fr;
        te[tid] = sinf(a);
        te[tid + 32] = cosf(a);
    }
    __syncthreads();
    float acc = b1[tid];
    for (int k = 0; k < 64; ++k) acc += te[k] * W1[k * 128 + tid];
    h1[tid] = silu_f(acc);
    __syncthreads();
    float acc2 = b2[tid];
    for (int k = 0; k < 128; ++k) acc2 += h1[k] * W2[k * 128 + tid];
    t_emb[b * 128 + tid] = acc2;
}

__global__ void k_embproj(const float* __restrict__ emb, const float* __restrict__ W,
                          const float* __restrict__ bias, float* __restrict__ outp) {
    int tid = threadIdx.x;       // 512 threads
    int a = tid >> 7, j = tid & 127;
    float acc = bias[j];
    for (int k = 0; k < 128; ++k) acc += emb[a * 128 + k] * W[k * 128 + j];
    outp[a * 128 + j] = acc;
}

__global__ void k_hinit(const int* __restrict__ at, const float* __restrict__ embp,
                        const float* __restrict__ temb, float* __restrict__ h,
                        _Float16* __restrict__ h16) {
    size_t idx4 = (size_t)blockIdx.x * 256 + threadIdx.x;   // over B*N*H/4
    size_t e0 = idx4 * 4;
    int j = (int)(e0 % H_);
    size_t bn = e0 / H_;
    int n = (int)(bn % N_);
    int b = (int)(bn / N_);
    int a = at[n];
    float4 ep = *(const float4*)(embp + a * H_ + j);
    float4 tv = *(const float4*)(temb + b * H_ + j);
    float4 r = make_float4(ep.x + tv.x, ep.y + tv.y, ep.z + tv.z, ep.w + tv.w);
    ((float4*)h)[idx4] = r;
    f16x4v o;
    o[0] = (_Float16)r.x; o[1] = (_Float16)r.y; o[2] = (_Float16)r.z; o[3] = (_Float16)r.w;
    *(f16x4v*)(h16 + e0) = o;
}

__global__ void k_xcopy(const float* __restrict__ x, float* __restrict__ xb) {
    int i = blockIdx.x * 256 + threadIdx.x;  // 480000 exact
    xb[i] = x[i];
}

// ---------------- MFMA GEMM core ----------------
// A: wave's 16 rows in LDS fp16 (base pre-offset to wave block, row stride RS).
// Wf: frag-layout fp16 weights. acc[nt] covers C rows quad*4+reg, col nt*16+ml.
template <int RS, int KT>
__device__ __forceinline__ void mfma_gemm(const _Float16* Asw, const _Float16* __restrict__ Wf,
                                          f32x4 (&acc)[8], int ml, int quad, int lane) {
    #pragma unroll
    for (int kt = 0; kt < KT; ++kt) {
        f16x8 a = *(const f16x8*)(Asw + ml * RS + kt * 32 + quad * 8);
        #pragma unroll
        for (int nt = 0; nt < 8; ++nt) {
            f16x8 b = *(const f16x8*)(Wf + (((kt * 8 + nt) * 64 + lane) * 8));
            acc[nt] = __builtin_amdgcn_mfma_f32_16x16x32_f16(a, b, acc[nt], 0, 0, 0);
        }
    }
}

// ---------------- fp32 tiled GEMM (k_out2 only) ----------------
template <int STRIDE, int K>
__device__ __forceinline__ void gemm_t(const float* As, const float* __restrict__ W,
                                       float (&acc)[4][8], int r4, int c) {
    const float4* Wv = (const float4*)W;
    #pragma unroll 2
    for (int k = 0; k < K; k += 4) {
        float a[4][4];
        #pragma unroll
        for (int i = 0; i < 4; ++i)
            *(float4*)a[i] = *(const float4*)(As + (r4 + i) * STRIDE + k);
        #pragma unroll
        for (int kk = 0; kk < 4; ++kk) {
            float4 w0 = Wv[(k + kk) * 32 + c * 2];
            float4 w1 = Wv[(k + kk) * 32 + c * 2 + 1];
            #pragma unroll
            for (int i = 0; i < 4; ++i) {
                float av = a[i][kk];
                acc[i][0] += av * w0.x; acc[i][1] += av * w0.y;
                acc[i][2] += av * w0.z; acc[i][3] += av * w0.w;
                acc[i][4] += av * w1.x; acc[i][5] += av * w1.y;
                acc[i][6] += av * w1.z; acc[i][7] += av * w1.w;
            }
        }
    }
}

__device__ __forceinline__ void bias_init(float (&acc)[4][8], const float* __restrict__ bias, int c) {
    float4 b0 = ((const float4*)bias)[c * 2];
    float4 b1 = ((const float4*)bias)[c * 2 + 1];
    #pragma unroll
    for (int i = 0; i < 4; ++i) {
        acc[i][0] = b0.x; acc[i][1] = b0.y; acc[i][2] = b0.z; acc[i][3] = b0.w;
        acc[i][4] = b1.x; acc[i][5] = b1.y; acc[i][6] = b1.z; acc[i][7] = b1.w;
    }
}

// ---------------- per-layer kernels ----------------

// 64 edges/block, 4 waves; each wave owns 16 rows end-to-end (staging thread
// t>>2 lands in the same wave's rows, so no cross-wave data flow).
__global__ __launch_bounds__(256) void k_edge_mfma(
    const _Float16* __restrict__ h16, const float* __restrict__ xcur,
    const int* __restrict__ bond,
    const float* __restrict__ Wm1, const float* __restrict__ bm1,
    const _Float16* __restrict__ Wm1f,
    const float* __restrict__ bm2, const _Float16* __restrict__ Wm2f,
    const float* __restrict__ bc1, const _Float16* __restrict__ Wc1f,
    const float* __restrict__ Wc2,
    _Float16* __restrict__ m16, float* __restrict__ cw_out) {
    __shared__ _Float16 As[64 * ERS];
    __shared__ float ds_s[64];
    int tid = threadIdx.x;
    {
        int el = tid >> 2, q = tid & 3;
        int be = blockIdx.x * 64 + el;
        int b = be / E_, e = be - b * E_;
        int s = bond[2 * e], d = bond[2 * e + 1];
        const _Float16* hs = h16 + ((size_t)b * N_ + s) * H_;
        const _Float16* hd = h16 + ((size_t)b * N_ + d) * H_;
        #pragma unroll
        for (int j = 0; j < 4; ++j) {
            int c = q + 4 * j;
            *(f16x8*)(As + el * ERS + c * 8) = *(const f16x8*)(hs + c * 8);
            *(f16x8*)(As + el * ERS + 128 + c * 8) = *(const f16x8*)(hd + c * 8);
        }
        if (q == 0) {
            const float* xs = xcur + ((size_t)b * N_ + s) * 3;
            const float* xd = xcur + ((size_t)b * N_ + d) * 3;
            float dx = xd[0] - xs[0], dy = xd[1] - xs[1], dz = xd[2] - xs[2];
            ds_s[el] = sqrtf(dx * dx + dy * dy + dz * dz);
        }
    }
    __syncthreads();

    int lane = tid & 63, w = tid >> 6;
    int ml = lane & 15, quad = lane >> 4;
    _Float16* Asw = As + w * 16 * ERS;
    size_t be0 = (size_t)blockIdx.x * 64;
    const float* wd = Wm1 + 256 * H_;

    f32x4 acc[8];
    // ---- GEMM1: acc = bm1 + dist*wd + [h_s|h_d] @ Wm1[0:256]
    #pragma unroll
    for (int nt = 0; nt < 8; ++nt) {
        int col = nt * 16 + ml;
        float bb = bm1[col];
        float ww = wd[col];
        #pragma unroll
        for (int r = 0; r < 4; ++r) {
            float di = ds_s[w * 16 + quad * 4 + r];
            acc[nt][r] = bb + di * ww;
        }
    }
    mfma_gemm<ERS, 8>(Asw, Wm1f, acc, ml, quad, lane);
    __syncthreads();
    // silu -> m1 -> LDS cols 0..127
    #pragma unroll
    for (int nt = 0; nt < 8; ++nt)
        #pragma unroll
        for (int r = 0; r < 4; ++r)
            Asw[(quad * 4 + r) * ERS + nt * 16 + ml] = (_Float16)silu_f(acc[nt][r]);
    __syncthreads();

    // ---- GEMM2: m = silu(m1 @ Wm2 + bm2)
    #pragma unroll
    for (int nt = 0; nt < 8; ++nt) {
        float bb = bm2[nt * 16 + ml];
        #pragma unroll
        for (int r = 0; r < 4; ++r) acc[nt][r] = bb;
    }
    mfma_gemm<ERS, 4>(Asw, Wm2f, acc, ml, quad, lane);
    __syncthreads();
    #pragma unroll
    for (int nt = 0; nt < 8; ++nt)
        #pragma unroll
        for (int r = 0; r < 4; ++r) {
            _Float16 v16 = (_Float16)silu_f(acc[nt][r]);
            int row = quad * 4 + r;
            m16[(be0 + w * 16 + row) * H_ + nt * 16 + ml] = v16;
            Asw[row * ERS + 128 + nt * 16 + ml] = v16;   // m -> cols 128..255
        }
    __syncthreads();

    // ---- GEMM3: cw = silu(m @ Wc1 + bc1) @ Wc2
    #pragma unroll
    for (int nt = 0; nt < 8; ++nt) {
        float bb = bc1[nt * 16 + ml];
        #pragma unroll
        for (int r = 0; r < 4; ++r) acc[nt][r] = bb;
    }
    mfma_gemm<ERS, 4>(Asw + 128, Wc1f, acc, ml, quad, lane);
    float part[4] = {0.f, 0.f, 0.f, 0.f};
    #pragma unroll
    for (int nt = 0; nt < 8; ++nt) {
        float wv = Wc2[nt * 16 + ml];
        #pragma unroll
        for (int r = 0; r < 4; ++r) part[r] += silu_f(acc[nt][r]) * wv;
    }
    #pragma unroll
    for (int off = 1; off < 16; off <<= 1)
        #pragma unroll
        for (int r = 0; r < 4; ++r) part[r] += __shfl_xor(part[r], off, 64);
    if (ml == 0) {
        #pragma unroll
        for (int r = 0; r < 4; ++r)
            cw_out[be0 + w * 16 + quad * 4 + r] = part[r];
    }
}

__global__ void k_coord(const float* __restrict__ xcur, float* __restrict__ xnext,
                        const float* __restrict__ cw, const int* __restrict__ bond,
                        const int* __restrict__ indptr, const int* __restrict__ adj) {
    int idx = blockIdx.x * 256 + threadIdx.x;   // B*N exact
    int b = idx / N_;
    int n = idx - b * N_;
    const float* xb = xcur + (size_t)b * N_ * 3;
    int p0 = indptr[n], p1 = indptr[n + 1];
    float ax = 0.f, ay = 0.f, az = 0.f;
    for (int p = p0; p < p1; ++p) {
        int a = adj[p];
        int e = a >> 1;
        float sgn = (a & 1) ? 1.f : -1.f;
        int s = bond[2 * e], d = bond[2 * e + 1];
        float dx = xb[d * 3 + 0] - xb[s * 3 + 0];
        float dy = xb[d * 3 + 1] - xb[s * 3 + 1];
        float dz = xb[d * 3 + 2] - xb[s * 3 + 2];
        float dist = sqrtf(dx * dx + dy * dy + dz * dz);
        float w = cw[(size_t)b * E_ + e] * sgn / (dist + 1e-8f);
        ax += dx * w; ay += dy * w; az += dz * w;
    }
    float cnt = (float)max(p1 - p0, 1);
    xnext[(size_t)idx * 3 + 0] = xb[n * 3 + 0] + ax / cnt;
    xnext[(size_t)idx * 3 + 1] = xb[n * 3 + 1] + ay / cnt;
    xnext[(size_t)idx * 3 + 2] = xb[n * 3 + 2] + az / cnt;
}

// 64 nodes/block: u = silu(h@Wn1a + agg@Wn1b + bn1); h += u@Wn2 + bn2
__global__ __launch_bounds__(256) void k_node_mfma(
    float* __restrict__ h, _Float16* __restrict__ h16,
    const _Float16* __restrict__ m16,
    const int* __restrict__ indptr, const int* __restrict__ adj,
    const float* __restrict__ bn1, const _Float16* __restrict__ Wn1f,
    const float* __restrict__ bn2, const _Float16* __restrict__ Wn2f) {
    __shared__ _Float16 As[64 * NRS];
    int tid = threadIdx.x;
    int el = tid >> 2, q = tid & 3;
    int be = blockIdx.x * 64 + el;   // b*N + n
    int b = be / N_, n = be - b * N_;
    // stage h tile (fp16)
    {
        const _Float16* hr = h16 + (size_t)be * H_;
        #pragma unroll
        for (int j = 0; j < 4; ++j) {
            int c = q + 4 * j;
            *(f16x8*)(As + el * NRS + c * 8) = *(const f16x8*)(hr + c * 8);
        }
    }
    __syncthreads();

    int lane = tid & 63, w = tid >> 6;
    int ml = lane & 15, quad = lane >> 4;
    _Float16* Asw = As + w * 16 * NRS;
    size_t be0 = (size_t)blockIdx.x * 64;

    f32x4 acc[8];
    #pragma unroll
    for (int nt = 0; nt < 8; ++nt) {
        float bb = bn1[nt * 16 + ml];
        #pragma unroll
        for (int r = 0; r < 4; ++r) acc[nt][r] = bb;
    }
    mfma_gemm<NRS, 4>(Asw, Wn1f, acc, ml, quad, lane);     // + h @ Wn1a
    __syncthreads();
    // agg gather -> As (overwrites h tile)
    {
        float ag[4][8];
        #pragma unroll
        for (int j = 0; j < 4; ++j)
            #pragma unroll
            for (int i = 0; i < 8; ++i) ag[j][i] = 0.f;
        int p0 = indptr[n], p1 = indptr[n + 1];
        for (int p = p0; p < p1; ++p) {
            int e = adj[p] >> 1;
            const _Float16* mp = m16 + ((size_t)b * E_ + e) * H_;
            #pragma unroll
            for (int j = 0; j < 4; ++j) {
                f16x8 v = *(const f16x8*)(mp + (q + 4 * j) * 8);
                #pragma unroll
                for (int i = 0; i < 8; ++i) ag[j][i] += (float)v[i];
            }
        }
        #pragma unroll
        for (int j = 0; j < 4; ++j) {
            f16x8 o;
            #pragma unroll
            for (int i = 0; i < 8; ++i) o[i] = (_Float16)ag[j][i];
            *(f16x8*)(As + el * NRS + (q + 4 * j) * 8) = o;
        }
    }
    __syncthreads();
    mfma_gemm<NRS, 4>(Asw, Wn1f + 4 * 8 * 64 * 8, acc, ml, quad, lane);  // + agg @ Wn1b
    __syncthreads();
    // u -> As
    #pragma unroll
    for (int nt = 0; nt < 8; ++nt)
        #pragma unroll
        for (int r = 0; r < 4; ++r)
            Asw[(quad * 4 + r) * NRS + nt * 16 + ml] = (_Float16)silu_f(acc[nt][r]);
    __syncthreads();
    f32x4 acc2[8];
    #pragma unroll
    for (int nt = 0; nt < 8; ++nt) {
        float bb = bn2[nt * 16 + ml];
        #pragma unroll
        for (int r = 0; r < 4; ++r) acc2[nt][r] = bb;
    }
    mfma_gemm<NRS, 4>(Asw, Wn2f, acc2, ml, quad, lane);
    // residual (fp32 h) + writeback h and h16
    #pragma unroll
    for (int nt = 0; nt < 8; ++nt)
        #pragma unroll
        for (int r = 0; r < 4; ++r) {
            int row = w * 16 + quad * 4 + r;
            size_t g = (size_t)(be0 + row) * H_ + nt * 16 + ml;
            float v = h[g] + acc2[nt][r];
            h[g] = v;
            h16[g] = (_Float16)v;
        }
}

// out = silu(h@Wo1+bo1)@Wo2 + bo2 + (xfin - xorig)
__global__ __launch_bounds__(256) void k_out2(
    const float* __restrict__ h, const float* __restrict__ xfin, const float* __restrict__ xorig,
    const float* __restrict__ Wo1, const float* __restrict__ bo1,
    const float* __restrict__ Wo2, const float* __restrict__ bo2,
    float* __restrict__ out) {
    __shared__ float As[64 * TS];
    __shared__ float red[64 * 48];
    int tid = threadIdx.x;
    {
        int nl = tid >> 2, q = tid & 3;
        size_t row = (size_t)blockIdx.x * 64 + nl;
        const float4* hr = (const float4*)(h + row * H_);
        #pragma unroll
        for (int j = 0; j < 8; ++j) {
            int f4 = j * 4 + q;
            *(float4*)(As + nl * TS + f4 * 4) = hr[f4];
        }
    }
    __syncthreads();
    int r4 = (tid >> 4) * 4, c = tid & 15;
    float acc[4][8];
    bias_init(acc, bo1, c);
    gemm_t<TS, 128>(As, Wo1, acc, r4, c);
    #pragma unroll
    for (int i = 0; i < 4; ++i) {
        float p0 = 0.f, p1 = 0.f, p2 = 0.f;
        #pragma unroll
        for (int j = 0; j < 8; ++j) {
            float u = silu_f(acc[i][j]);
            int col = c * 8 + j;
            p0 += u * Wo2[col * 3 + 0];
            p1 += u * Wo2[col * 3 + 1];
            p2 += u * Wo2[col * 3 + 2];
        }
        red[(r4 + i) * 48 + c * 3 + 0] = p0;
        red[(r4 + i) * 48 + c * 3 + 1] = p1;
        red[(r4 + i) * 48 + c * 3 + 2] = p2;
    }
    __syncthreads();
    if (tid < 192) {
        int row = tid / 3, jj = tid - row * 3;
        float s = 0.f;
        #pragma unroll
        for (int cc = 0; cc < 16; ++cc) s += red[row * 48 + cc * 3 + jj];
        size_t grow = (size_t)blockIdx.x * 64 + row;
        out[grow * 3 + jj] = s + bo2[jj] + xfin[grow * 3 + jj] - xorig[grow * 3 + jj];
    }
}

// ---------------- launcher ----------------

extern "C" void kernel_launch(void* const* d_in, const int* in_sizes, int n_in,
                              void* d_out, int out_size, void* d_ws, size_t ws_size,
                              hipStream_t stream) {
    const float* x = (const float*)d_in[0];
    const float* t = (const float*)d_in[1];
    const int* atom_types = (const int*)d_in[2];
    const int* bond = (const int*)d_in[3];
    const float* emb_table = (const float*)d_in[4];
    const float* W_t1 = (const float*)d_in[5];
    const float* b_t1 = (const float*)d_in[6];
    const float* W_t2 = (const float*)d_in[7];
    const float* b_t2 = (const float*)d_in[8];
    const float* W_node = (const float*)d_in[9];
    const float* b_node = (const float*)d_in[10];
    const float* Wm1 = (const float*)d_in[11];
    const float* bm1 = (const float*)d_in[12];
    const float* Wm2 = (const float*)d_in[13];
    const float* bm2 = (const float*)d_in[14];
    const float* Wn1 = (const float*)d_in[15];
    const float* bn1 = (const float*)d_in[16];
    const float* Wn2 = (const float*)d_in[17];
    const float* bn2 = (const float*)d_in[18];
    const float* Wc1 = (const float*)d_in[19];
    const float* bc1 = (const float*)d_in[20];
    const float* Wc2 = (const float*)d_in[21];
    const float* W_o1 = (const float*)d_in[22];
    const float* b_o1 = (const float*)d_in[23];
    const float* W_o2 = (const float*)d_in[24];
    const float* b_o2 = (const float*)d_in[25];
    float* out = (float*)d_out;

    char* p = (char*)d_ws;
    auto alloc = [&](size_t bytes) -> void* {
        void* r = (void*)p;
        p += (bytes + 255) & ~(size_t)255;
        return r;
    };
    // ~170 MB total (R1's 252 MB layout fit; R2's 415 MB overflowed)
    float* t_emb = (float*)alloc((size_t)B_ * H_ * 4);
    float* emb_proj = (float*)alloc((size_t)A_ * H_ * 4);
    int* deg = (int*)alloc((size_t)N_ * 4);
    int* indptr = (int*)alloc((size_t)(N_ + 1) * 4);
    int* cursor = (int*)alloc((size_t)N_ * 4);
    int* adj = (int*)alloc((size_t)2 * E_ * 4);
    float* xb0 = (float*)alloc((size_t)B_ * N_ * 3 * 4);
    float* xb1 = (float*)alloc((size_t)B_ * N_ * 3 * 4);
    float* cw = (float*)alloc((size_t)B_ * E_ * 4);
    float* h = (float*)alloc((size_t)B_ * N_ * H_ * 4);
    _Float16* h16 = (_Float16*)alloc((size_t)B_ * N_ * H_ * 2);
    _Float16* m16 = (_Float16*)alloc((size_t)B_ * E_ * H_ * 2);
    _Float16* Wm1f = (_Float16*)alloc((size_t)L_ * 256 * H_ * 2);
    _Float16* Wm2f = (_Float16*)alloc((size_t)L_ * H_ * H_ * 2);
    _Float16* Wc1f = (_Float16*)alloc((size_t)L_ * H_ * H_ * 2);
    _Float16* Wn1f = (_Float16*)alloc((size_t)L_ * 256 * H_ * 2);
    _Float16* Wn2f = (_Float16*)alloc((size_t)L_ * H_ * H_ * 2);

    k_zero<<<(N_ + 255) / 256, 256, 0, stream>>>(deg, cursor);
    k_deg<<<(E_ + 255) / 256, 256, 0, stream>>>(bond, deg);
    k_scan<<<1, 1024, 0, stream>>>(deg, indptr);
    k_fill<<<(E_ + 255) / 256, 256, 0, stream>>>(bond, indptr, cursor, adj);
    k_temb<<<B_, 128, 0, stream>>>(t, W_t1, b_t1, W_t2, b_t2, t_emb);
    k_embproj<<<1, 512, 0, stream>>>(emb_table, W_node, b_node, emb_proj);
    k_hinit<<<(B_ * N_ * H_ / 4) / 256, 256, 0, stream>>>(atom_types, emb_proj, t_emb, h, h16);
    k_xcopy<<<(B_ * N_ * 3) / 256, 256, 0, stream>>>(x, xb0);
    for (int l = 0; l < L_; ++l) {
        k_wprep<<<128, 256, 0, stream>>>(Wm1 + (size_t)l * 257 * H_, Wm1f + (size_t)l * 256 * H_, 256);
        k_wprep<<<64, 256, 0, stream>>>(Wm2 + (size_t)l * H_ * H_, Wm2f + (size_t)l * H_ * H_, 128);
        k_wprep<<<64, 256, 0, stream>>>(Wc1 + (size_t)l * H_ * H_, Wc1f + (size_t)l * H_ * H_, 128);
        k_wprep<<<128, 256, 0, stream>>>(Wn1 + (size_t)l * 2 * H_ * H_, Wn1f + (size_t)l * 256 * H_, 256);
        k_wprep<<<64, 256, 0, stream>>>(Wn2 + (size_t)l * H_ * H_, Wn2f + (size_t)l * H_ * H_, 128);
    }

    float* xc = xb0;
    float* xn = xb1;
    for (int l = 0; l < L_; ++l) {
        k_edge_mfma<<<(B_ * E_) / 64, 256, 0, stream>>>(
            h16, xc, bond,
            Wm1 + (size_t)l * 257 * H_, bm1 + l * H_, Wm1f + (size_t)l * 256 * H_,
            bm2 + l * H_, Wm2f + (size_t)l * H_ * H_,
            bc1 + l * H_, Wc1f + (size_t)l * H_ * H_,
            Wc2 + (size_t)l * H_, m16, cw);
        k_coord<<<(B_ * N_) / 256, 256, 0, stream>>>(xc, xn, cw, bond, indptr, adj);
        k_node_mfma<<<(B_ * N_) / 64, 256, 0, stream>>>(
            h, h16, m16, indptr, adj,
            bn1 + l * H_, Wn1f + (size_t)l * 256 * H_,
            bn2 + l * H_, Wn2f + (size_t)l * H_ * H_);
        float* tmp = xc; xc = xn; xn = tmp;
    }
    k_out2<<<(B_ * N_) / 64, 256, 0, stream>>>(h, xc, x, W_o1, b_o1, W_o2, b_o2, out);
}